// Round 1
// baseline (1929.344 us; speedup 1.0000x reference)
//
#include <hip/hip_runtime.h>
#include <hip/hip_bf16.h>

#define NN 50000
#define NR 8
#define DIM 128
#define NE 800000

using floatx4 = __attribute__((ext_vector_type(4))) float;
using bf16x8  = __attribute__((ext_vector_type(8))) __bf16;

// ---------------- workspace layout (in floats) ----------------
// zeroed region: [0, 400128)
#define OFF_CNT  0u          // 400000: int counts, then float inv in-place
#define OFF_X1   400000u     // 128: X1sum (atomic accum, zeroed)
#define OFF_S2   400128u     // 1024: S2 final (written by reduce)
#define OFF_S2P  401152u     // 1024*1024: S2 partials
#define OFF_XB   1449728u    // 6.4M bf16 = 3.2M floats: x_emb in bf16
#define OFF_ACC  4649728u    // 6.4M: layer-1 pre-relu accumulator
#define OFF_Y    11049728u   // 6.4M: per-relation transformed features
// total 17,449,728 floats = 69.8 MB

// ---------------- bf16 cast of x_emb ----------------
__global__ void cvt_bf16_k(const float* __restrict__ x, __bf16* __restrict__ xb, int n) {
    int i = blockIdx.x * 256 + threadIdx.x;
    if (i < n) xb[i] = (__bf16)x[i];
}

// ---------------- per-(rel,target) edge counts ----------------
__global__ void count_k(const int* __restrict__ r, const int* __restrict__ t, int* __restrict__ cnt) {
    int e = blockIdx.x * 256 + threadIdx.x;
    if (e < NE) atomicAdd(&cnt[r[e] * NN + t[e]], 1);
}

__global__ void inv_k(float* __restrict__ ci) {
    int i = blockIdx.x * 256 + threadIdx.x;
    if (i < NR * NN) {
        int c = reinterpret_cast<int*>(ci)[i];
        ci[i] = 1.0f / (float)(c > 1 ? c : 1);
    }
}

// ---------------- C[M,128] = A_bf16[M,128] @ B_f32[128,128] (+bias) ----------------
// 256 thr = 4 waves; block covers 64 rows x 128 cols; mfma_f32_16x16x32_bf16.
// B is converted to bf16 and packed into LDS in MFMA fragment order:
//   frag_id = (k>>5)*8 + (n>>4); lane = (n&15) | (((k>>3)&3)<<4); j = k&7.
__global__ __launch_bounds__(256) void gemm_bf16_k128(
    const __bf16* __restrict__ A, const float* __restrict__ B,
    float* __restrict__ C, const float* __restrict__ bias, int M)
{
    __shared__ __attribute__((aligned(16))) __bf16 bfrag[32 * 64 * 8];  // 32 KB
    const int tid = threadIdx.x;
#pragma unroll
    for (int a = 0; a < 8; ++a) {
        int idx = tid + a * 256;          // 0..2047 = (frag_id, lane)
        int lt = idx & 63;
        int fid = idx >> 6;
        int s = fid >> 3, nt = fid & 7;
        int n = nt * 16 + (lt & 15);
        int kb = s * 32 + (lt >> 4) * 8;
        bf16x8 v;
#pragma unroll
        for (int j = 0; j < 8; ++j) v[j] = (__bf16)B[(kb + j) * DIM + n];
        *reinterpret_cast<bf16x8*>(&bfrag[idx * 8]) = v;
    }
    __syncthreads();

    const int wave = tid >> 6, lane = tid & 63;
    const int quad = lane >> 4;
    const int m0 = blockIdx.x * 64 + wave * 16;
    int mA = m0 + (lane & 15);
    if (mA > M - 1) mA = M - 1;                 // clamp OOB A reads; stores guarded below
    const __bf16* Ap = A + (size_t)mA * DIM + quad * 8;

    floatx4 acc[8];
#pragma unroll
    for (int i = 0; i < 8; ++i) acc[i] = (floatx4)0.f;

#pragma unroll
    for (int s = 0; s < 4; ++s) {
        bf16x8 af = *reinterpret_cast<const bf16x8*>(Ap + s * 32);
        const __bf16* bp = &bfrag[(s * 8) * 512 + lane * 8];
#pragma unroll
        for (int nt = 0; nt < 8; ++nt) {
            bf16x8 bf = *reinterpret_cast<const bf16x8*>(bp + nt * 512);
            acc[nt] = __builtin_amdgcn_mfma_f32_16x16x32_bf16(af, bf, acc[nt], 0, 0, 0);
        }
    }

    const int rb = m0 + quad * 4, col = lane & 15;
#pragma unroll
    for (int nt = 0; nt < 8; ++nt) {
        int c = nt * 16 + col;
        float badd = bias ? bias[c] : 0.f;
#pragma unroll
        for (int i = 0; i < 4; ++i) {
            int rr = rb + i;
            if (rr < M) C[(size_t)rr * DIM + c] = acc[nt][i] + badd;
        }
    }
}

// ---------------- layer-1 scatter: acc[t] += Y[h] * inv_c[rel,t] (edges of rel) ----------------
__global__ __launch_bounds__(256) void scatter_k(
    const int* __restrict__ h, const int* __restrict__ r, const int* __restrict__ t,
    const float* __restrict__ Y, const float* __restrict__ inv,
    float* __restrict__ acc, int rel)
{
    const int slot = threadIdx.x >> 5, l = threadIdx.x & 31;
    for (int e = blockIdx.x * 8 + slot; e < NE; e += gridDim.x * 8) {
        if (r[e] != rel) continue;
        int he = h[e], te = t[e];
        float sc = inv[rel * NN + te];
        floatx4 y = *reinterpret_cast<const floatx4*>(Y + (size_t)he * DIM + l * 4);
        float* ap = acc + (size_t)te * DIM + l * 4;
        atomicAdd(ap + 0, y[0] * sc);
        atomicAdd(ap + 1, y[1] * sc);
        atomicAdd(ap + 2, y[2] * sc);
        atomicAdd(ap + 3, y[3] * sc);
    }
}

// ---------------- layer-2 edge reduction: S2 partials (relu applied on read) ----------------
__global__ __launch_bounds__(512) void s2_k(
    const int* __restrict__ h, const int* __restrict__ r, const int* __restrict__ t,
    const float* __restrict__ acc, const float* __restrict__ inv, float* __restrict__ S2P)
{
    __shared__ float s2l[4][NR * DIM];
    const int d = threadIdx.x & 127, slot = threadIdx.x >> 7;
    for (int i = threadIdx.x; i < 4 * NR * DIM; i += 512) (&s2l[0][0])[i] = 0.f;
    __syncthreads();
    for (int e = blockIdx.x * 4 + slot; e < NE; e += gridDim.x * 4) {
        int he = h[e], re = r[e], te = t[e];
        float v = fmaxf(acc[(size_t)he * DIM + d], 0.f) * inv[re * NN + te];
        s2l[slot][re * DIM + d] += v;   // thread owns column d -> race-free
    }
    __syncthreads();
    if (threadIdx.x < 128) {
        for (int i = 0; i < NR; ++i)
            S2P[(size_t)blockIdx.x * 1024 + i * DIM + d] =
                s2l[0][i * DIM + d] + s2l[1][i * DIM + d] + s2l[2][i * DIM + d] + s2l[3][i * DIM + d];
    }
}

__global__ void s2_reduce_k(const float* __restrict__ S2P, float* __restrict__ S2) {
    int col = blockIdx.x * 256 + threadIdx.x;   // 0..1023
    float s = 0.f;
    for (int row = 0; row < 1024; ++row) s += S2P[(size_t)row * 1024 + col];
    S2[col] = s;
}

// ---------------- X1sum = sum_n relu(acc[n,:]) ----------------
__global__ __launch_bounds__(256) void x1sum_k(const float* __restrict__ acc, float* __restrict__ X1) {
    const int d = threadIdx.x & 127, slot = threadIdx.x >> 7;
    float s = 0.f;
    for (int n = blockIdx.x * 2 + slot; n < NN; n += gridDim.x * 2)
        s += fmaxf(acc[(size_t)n * DIM + d], 0.f);
    atomicAdd(&X1[d], s);
}

// ---------------- final: out = (S2.W2 + X1.root2)/N + b2 ----------------
__global__ __launch_bounds__(128) void final_k(
    const float* __restrict__ S2, const float* __restrict__ X1,
    const float* __restrict__ W2, const float* __restrict__ root2,
    const float* __restrict__ b2, float* __restrict__ out)
{
    const int o = threadIdx.x;
    float s = 0.f;
    for (int rr = 0; rr < NR; ++rr)
        for (int d = 0; d < DIM; ++d)
            s += S2[rr * DIM + d] * W2[((size_t)rr * DIM + d) * DIM + o];
    for (int d = 0; d < DIM; ++d)
        s += X1[d] * root2[d * DIM + o];
    out[o] = s * (1.0f / NN) + b2[o];
}

extern "C" void kernel_launch(void* const* d_in, const int* in_sizes, int n_in,
                              void* d_out, int out_size, void* d_ws, size_t ws_size,
                              hipStream_t stream)
{
    const int*   h     = (const int*)d_in[0];
    const int*   r     = (const int*)d_in[1];
    const int*   t     = (const int*)d_in[2];
    const float* x_emb = (const float*)d_in[3];
    const float* W1    = (const float*)d_in[4];
    const float* root1 = (const float*)d_in[5];
    const float* b1    = (const float*)d_in[6];
    const float* W2    = (const float*)d_in[7];
    const float* root2 = (const float*)d_in[8];
    const float* b2    = (const float*)d_in[9];

    float* ws  = (float*)d_ws;
    float* cnt = ws + OFF_CNT;
    float* X1  = ws + OFF_X1;
    float* S2  = ws + OFF_S2;
    float* S2P = ws + OFF_S2P;
    __bf16* xb = (__bf16*)(ws + OFF_XB);
    float* acc = ws + OFF_ACC;
    float* Y   = ws + OFF_Y;

    // zero counts + X1sum (re-poisoned to 0xAA before every timed launch)
    hipMemsetAsync(ws, 0, (size_t)400128 * sizeof(float), stream);

    cvt_bf16_k<<<25000, 256, 0, stream>>>(x_emb, xb, NN * DIM);
    count_k<<<3125, 256, 0, stream>>>(r, t, (int*)cnt);
    inv_k<<<1563, 256, 0, stream>>>(cnt);

    // acc = x_emb @ root1 + b1
    gemm_bf16_k128<<<782, 256, 0, stream>>>(xb, root1, acc, b1, NN);

    // per relation: Y = x_emb @ W1[rel]; acc[t] += Y[h] * inv_c
    for (int rel = 0; rel < NR; ++rel) {
        gemm_bf16_k128<<<782, 256, 0, stream>>>(xb, W1 + (size_t)rel * DIM * DIM, Y, nullptr, NN);
        scatter_k<<<2048, 256, 0, stream>>>(h, r, t, Y, cnt, acc, rel);
    }

    // layer 2 collapses to two reductions (mean over nodes commutes with W2/root2)
    s2_k<<<1024, 512, 0, stream>>>(h, r, t, acc, cnt, S2P);
    s2_reduce_k<<<4, 256, 0, stream>>>(S2P, S2);
    x1sum_k<<<256, 256, 0, stream>>>(acc, X1);
    final_k<<<1, 128, 0, stream>>>(S2, X1, W2, root2, b2, (float*)d_out);
}

// Round 2
// 532.932 us; speedup vs baseline: 3.6202x; 3.6202x over previous
//
#include <hip/hip_runtime.h>
#include <hip/hip_bf16.h>

#define NN 50000
#define NR 8
#define DIM 128
#define NE 800000

using floatx4 = __attribute__((ext_vector_type(4))) float;
using bf16x8  = __attribute__((ext_vector_type(8))) __bf16;
using bf16x4  = __attribute__((ext_vector_type(4))) __bf16;

// ---------------- workspace layout (in floats) ----------------
// zeroed region: [0, 801152)
#define OFF_CNT   0u         // 400000: int counts -> float inv in place
#define OFF_WSUM  400000u    // 400000: wsum[r*NN+h] fp32 atomic accum
#define OFF_S2    800000u    // 1024: S2 (atomic accum)
#define OFF_X1    801024u    // 128: X1sum (atomic accum)
#define OFF_OFFS  801152u    // 400000 ints: CSR offsets (end-offsets after fill)
#define OFF_PART  1201152u   // 512 ints: scan partials
#define OFF_EH    1201664u   // 800000 ints: CSR-sorted edge head indices
#define OFF_XB    2001664u   // 6.4M bf16: x_emb in bf16
#define OFF_ACC   5201664u   // 6.4M floats: layer-1 pre-relu accumulator
#define OFF_YB    11601664u  // 6.4M bf16: per-relation transformed features
// total 14,801,664 floats = 59.2 MB

// ---------------- bf16 cast of x_emb ----------------
__global__ void cvt_bf16_k(const float* __restrict__ x, __bf16* __restrict__ xb, int n) {
    int i = blockIdx.x * 256 + threadIdx.x;
    if (i < n) xb[i] = (__bf16)x[i];
}

// ---------------- per-(rel,target) edge counts ----------------
__global__ void count_k(const int* __restrict__ r, const int* __restrict__ t, int* __restrict__ cnt) {
    int e = blockIdx.x * 256 + threadIdx.x;
    if (e < NE) atomicAdd(&cnt[r[e] * NN + t[e]], 1);
}

__global__ void inv_k(float* __restrict__ ci) {
    int i = blockIdx.x * 256 + threadIdx.x;
    if (i < NR * NN) {
        int c = reinterpret_cast<int*>(ci)[i];
        ci[i] = 1.0f / (float)(c > 1 ? c : 1);
    }
}

// ---------------- 3-pass exclusive scan over 400000 ints ----------------
__global__ __launch_bounds__(256) void scanA_k(const int* __restrict__ cnt, int* __restrict__ offs,
                                               int* __restrict__ part) {
    __shared__ int lds[256];
    const int tid = threadIdx.x;
    const int base = blockIdx.x * 1024 + tid * 4;
    int v[4] = {0, 0, 0, 0};
    if (base + 3 < NR * NN) {
        int4 q = *reinterpret_cast<const int4*>(cnt + base);
        v[0] = q.x; v[1] = q.y; v[2] = q.z; v[3] = q.w;
    } else {
#pragma unroll
        for (int j = 0; j < 4; ++j) if (base + j < NR * NN) v[j] = cnt[base + j];
    }
    int tsum = v[0] + v[1] + v[2] + v[3];
    lds[tid] = tsum;
    __syncthreads();
#pragma unroll
    for (int off = 1; off < 256; off <<= 1) {
        int val = (tid >= off) ? lds[tid - off] : 0;
        __syncthreads();
        if (tid >= off) lds[tid] += val;
        __syncthreads();
    }
    int excl = lds[tid] - tsum;
    int run = excl;
#pragma unroll
    for (int j = 0; j < 4; ++j) {
        if (base + j < NR * NN) offs[base + j] = run;
        run += v[j];
    }
    if (tid == 255) part[blockIdx.x] = lds[255];
}

__global__ __launch_bounds__(512) void scanB_k(int* __restrict__ part) {
    __shared__ int lds[512];
    const int tid = threadIdx.x;
    int v = (tid < 391) ? part[tid] : 0;
    lds[tid] = v;
    __syncthreads();
#pragma unroll
    for (int off = 1; off < 512; off <<= 1) {
        int val = (tid >= off) ? lds[tid - off] : 0;
        __syncthreads();
        if (tid >= off) lds[tid] += val;
        __syncthreads();
    }
    part[tid] = lds[tid] - v;  // exclusive
}

__global__ __launch_bounds__(256) void scanC_k(int* __restrict__ offs, const int* __restrict__ part) {
    const int base = blockIdx.x * 1024 + threadIdx.x * 4;
    const int add = part[blockIdx.x];
#pragma unroll
    for (int j = 0; j < 4; ++j)
        if (base + j < NR * NN) offs[base + j] += add;
}

// ---------------- CSR fill: eh sorted by (rel,t); offs becomes end-offsets ----------------
__global__ void fill_k(const int* __restrict__ h, const int* __restrict__ r, const int* __restrict__ t,
                       int* __restrict__ offs, int* __restrict__ eh) {
    int e = blockIdx.x * 256 + threadIdx.x;
    if (e < NE) {
        int seg = r[e] * NN + t[e];
        int pos = atomicAdd(&offs[seg], 1);
        eh[pos] = h[e];
    }
}

// ---------------- wsum[r,h] += inv[r,t] per edge (scalar atomics) ----------------
__global__ void wsum_k(const int* __restrict__ h, const int* __restrict__ r, const int* __restrict__ t,
                       const float* __restrict__ inv, float* __restrict__ wsum) {
    int e = blockIdx.x * 256 + threadIdx.x;
    if (e < NE) {
        int re = r[e];
        atomicAdd(&wsum[re * NN + h[e]], inv[re * NN + t[e]]);
    }
}

// ---------------- C[M,128] = A_bf16[M,128] @ B_f32[128,128] (+bias) ----------------
// BF16OUT=false: C fp32 + bias; BF16OUT=true: C bf16, no bias.
template <bool BF16OUT>
__global__ __launch_bounds__(256) void gemm_bf16_k128(
    const __bf16* __restrict__ A, const float* __restrict__ B,
    void* __restrict__ Cv, const float* __restrict__ bias, int M)
{
    __shared__ __attribute__((aligned(16))) __bf16 bfrag[32 * 64 * 8];  // 32 KB
    const int tid = threadIdx.x;
#pragma unroll
    for (int a = 0; a < 8; ++a) {
        int idx = tid + a * 256;          // 0..2047 = (frag_id, lane)
        int lt = idx & 63;
        int fid = idx >> 6;
        int s = fid >> 3, nt = fid & 7;
        int n = nt * 16 + (lt & 15);
        int kb = s * 32 + (lt >> 4) * 8;
        bf16x8 v;
#pragma unroll
        for (int j = 0; j < 8; ++j) v[j] = (__bf16)B[(kb + j) * DIM + n];
        *reinterpret_cast<bf16x8*>(&bfrag[idx * 8]) = v;
    }
    __syncthreads();

    const int wave = tid >> 6, lane = tid & 63;
    const int quad = lane >> 4;
    const int m0 = blockIdx.x * 64 + wave * 16;
    int mA = m0 + (lane & 15);
    if (mA > M - 1) mA = M - 1;                 // clamp OOB A reads; stores guarded below
    const __bf16* Ap = A + (size_t)mA * DIM + quad * 8;

    floatx4 acc[8];
#pragma unroll
    for (int i = 0; i < 8; ++i) acc[i] = (floatx4)0.f;

#pragma unroll
    for (int s = 0; s < 4; ++s) {
        bf16x8 af = *reinterpret_cast<const bf16x8*>(Ap + s * 32);
        const __bf16* bp = &bfrag[(s * 8) * 512 + lane * 8];
#pragma unroll
        for (int nt = 0; nt < 8; ++nt) {
            bf16x8 bf = *reinterpret_cast<const bf16x8*>(bp + nt * 512);
            acc[nt] = __builtin_amdgcn_mfma_f32_16x16x32_bf16(af, bf, acc[nt], 0, 0, 0);
        }
    }

    const int rb = m0 + quad * 4, col = lane & 15;
#pragma unroll
    for (int nt = 0; nt < 8; ++nt) {
        int c = nt * 16 + col;
        float badd = (!BF16OUT && bias) ? bias[c] : 0.f;
#pragma unroll
        for (int i = 0; i < 4; ++i) {
            int rr = rb + i;
            if (rr < M) {
                if (BF16OUT)
                    ((__bf16*)Cv)[(size_t)rr * DIM + c] = (__bf16)acc[nt][i];
                else
                    ((float*)Cv)[(size_t)rr * DIM + c] = acc[nt][i] + badd;
            }
        }
    }
}

// ---------------- layer-1 CSR gather: acc[t] += inv[rel,t] * sum_{e in seg} Yb[h_e] ----------------
// One 32-lane slot per target; no atomics (slot owns the whole (rel,t) segment).
__global__ __launch_bounds__(256) void gather_rel_k(
    const int* __restrict__ offs, const int* __restrict__ eh, const float* __restrict__ inv,
    const __bf16* __restrict__ Yb, float* __restrict__ acc, int rel)
{
    const int slot = threadIdx.x >> 5, lane = threadIdx.x & 31;
    for (int tt = blockIdx.x * 8 + slot; tt < NN; tt += gridDim.x * 8) {
        int seg = rel * NN + tt;
        int start = (seg == 0) ? 0 : offs[seg - 1];
        int end = offs[seg];
        if (end == start) continue;
        float s0 = 0.f, s1 = 0.f, s2 = 0.f, s3 = 0.f;
        for (int i = start; i < end; ++i) {
            int he = eh[i];
            bf16x4 y = *reinterpret_cast<const bf16x4*>(Yb + (size_t)he * DIM + lane * 4);
            s0 += (float)y[0]; s1 += (float)y[1]; s2 += (float)y[2]; s3 += (float)y[3];
        }
        float sc = inv[seg];
        float* ap = acc + (size_t)tt * DIM + lane * 4;
        floatx4 a = *reinterpret_cast<floatx4*>(ap);
        a[0] += s0 * sc; a[1] += s1 * sc; a[2] += s2 * sc; a[3] += s3 * sc;
        *reinterpret_cast<floatx4*>(ap) = a;
    }
}

// ---------------- fused: S2[r,d] = sum_h wsum[r,h]*relu(acc[h,d]); X1[d] = sum_h relu(acc[h,d]) ----------------
__global__ __launch_bounds__(128) void s2x1_k(
    const float* __restrict__ acc, const float* __restrict__ wsum,
    float* __restrict__ S2, float* __restrict__ X1)
{
    const int d = threadIdx.x;
    float s[NR] = {0.f, 0.f, 0.f, 0.f, 0.f, 0.f, 0.f, 0.f};
    float x1 = 0.f;
    for (int n = blockIdx.x; n < NN; n += gridDim.x) {
        float v = fmaxf(acc[(size_t)n * DIM + d], 0.f);
        x1 += v;
#pragma unroll
        for (int rr = 0; rr < NR; ++rr) s[rr] += wsum[rr * NN + n] * v;
    }
#pragma unroll
    for (int rr = 0; rr < NR; ++rr) atomicAdd(&S2[rr * DIM + d], s[rr]);
    atomicAdd(&X1[d], x1);
}

// ---------------- final: out = (S2.W2 + X1.root2)/N + b2 ----------------
__global__ __launch_bounds__(128) void final_k(
    const float* __restrict__ S2, const float* __restrict__ X1,
    const float* __restrict__ W2, const float* __restrict__ root2,
    const float* __restrict__ b2, float* __restrict__ out)
{
    const int o = threadIdx.x;
    float s = 0.f;
    for (int rr = 0; rr < NR; ++rr)
        for (int d = 0; d < DIM; ++d)
            s += S2[rr * DIM + d] * W2[((size_t)rr * DIM + d) * DIM + o];
    for (int d = 0; d < DIM; ++d)
        s += X1[d] * root2[d * DIM + o];
    out[o] = s * (1.0f / NN) + b2[o];
}

extern "C" void kernel_launch(void* const* d_in, const int* in_sizes, int n_in,
                              void* d_out, int out_size, void* d_ws, size_t ws_size,
                              hipStream_t stream)
{
    const int*   h     = (const int*)d_in[0];
    const int*   r     = (const int*)d_in[1];
    const int*   t     = (const int*)d_in[2];
    const float* x_emb = (const float*)d_in[3];
    const float* W1    = (const float*)d_in[4];
    const float* root1 = (const float*)d_in[5];
    const float* b1    = (const float*)d_in[6];
    const float* W2    = (const float*)d_in[7];
    const float* root2 = (const float*)d_in[8];
    const float* b2    = (const float*)d_in[9];

    float* ws   = (float*)d_ws;
    float* cnt  = ws + OFF_CNT;     // ints then inv floats in place
    float* wsum = ws + OFF_WSUM;
    float* S2   = ws + OFF_S2;
    float* X1   = ws + OFF_X1;
    int*   offs = (int*)(ws + OFF_OFFS);
    int*   part = (int*)(ws + OFF_PART);
    int*   eh   = (int*)(ws + OFF_EH);
    __bf16* xb  = (__bf16*)(ws + OFF_XB);
    float* acc  = ws + OFF_ACC;
    __bf16* Yb  = (__bf16*)(ws + OFF_YB);

    // zero counts + wsum + S2 + X1 (ws re-poisoned to 0xAA before every timed launch)
    hipMemsetAsync(ws, 0, (size_t)801152 * sizeof(float), stream);

    cvt_bf16_k<<<25000, 256, 0, stream>>>(x_emb, xb, NN * DIM);
    count_k<<<3125, 256, 0, stream>>>(r, t, (int*)cnt);

    // exclusive scan cnt -> offs
    scanA_k<<<391, 256, 0, stream>>>((const int*)cnt, offs, part);
    scanB_k<<<1, 512, 0, stream>>>(part);
    scanC_k<<<391, 256, 0, stream>>>(offs, part);

    inv_k<<<1563, 256, 0, stream>>>(cnt);   // cnt -> inv in place
    fill_k<<<3125, 256, 0, stream>>>(h, r, t, offs, eh);   // offs -> end-offsets
    wsum_k<<<3125, 256, 0, stream>>>(h, r, t, cnt, wsum);

    // acc = x_emb @ root1 + b1
    gemm_bf16_k128<false><<<782, 256, 0, stream>>>(xb, root1, acc, b1, NN);

    // per relation: Yb = x_emb @ W1[rel] (bf16); acc[t] += inv * segment-sum of Yb[h]
    for (int rel = 0; rel < NR; ++rel) {
        gemm_bf16_k128<true><<<782, 256, 0, stream>>>(xb, W1 + (size_t)rel * DIM * DIM, Yb, nullptr, NN);
        gather_rel_k<<<6250, 256, 0, stream>>>(offs, eh, cnt, Yb, acc, rel);
    }

    // layer 2 collapses to dense contractions (mean over nodes commutes with W2/root2)
    s2x1_k<<<512, 128, 0, stream>>>(acc, wsum, S2, X1);
    final_k<<<1, 128, 0, stream>>>(S2, X1, W2, root2, b2, (float*)d_out);
}

// Round 3
// 458.552 us; speedup vs baseline: 4.2075x; 1.1622x over previous
//
#include <hip/hip_runtime.h>
#include <hip/hip_bf16.h>

#define NN 50000
#define NR 8
#define DIM 128
#define NE 800000
#define PAD 136   // A-tile row stride in bf16 (128 + 8): 2-way LDS conflicts only

using floatx4 = __attribute__((ext_vector_type(4))) float;
using bf16x8  = __attribute__((ext_vector_type(8))) __bf16;

// ---------------- workspace layout (in floats) ----------------
// zeroed region: [0, 801152)
#define OFF_CNT   0u         // 400000: int counts -> float inv in place (seg = t*8+r)
#define OFF_WSUM  400000u    // 400000: wsum[r*NN+h] fp32 atomic accum
#define OFF_S2    800000u    // 1024: S2 (atomic accum)
#define OFF_X1    801024u    // 128: X1sum (atomic accum)
#define OFF_OFFS  801152u    // 400000 ints: CSR offsets (end-offsets after fill)
#define OFF_PART  1201152u   // 512 ints: scan partials
#define OFF_EH    1201664u   // 800000 ints: CSR-sorted edge head indices
#define OFF_XB    2001664u   // 6.4M bf16: x_emb in bf16
#define OFF_WF    5201664u   // 9*2048*8 bf16 = 73728 floats: weights in MFMA frag order
#define OFF_ACC   5275392u   // 6.4M floats: layer-1 POST-relu activations
// total 11,675,392 floats = 46.7 MB

// ---------------- bf16 cast of x_emb (x4 vectorized) ----------------
__global__ void cvt_bf16_k(const float* __restrict__ x, __bf16* __restrict__ xb) {
    int i = (blockIdx.x * 256 + threadIdx.x) * 4;
    float4 v = *reinterpret_cast<const float4*>(x + i);
    __bf16 o[4] = {(__bf16)v.x, (__bf16)v.y, (__bf16)v.z, (__bf16)v.w};
    *reinterpret_cast<uint2*>(xb + i) = *reinterpret_cast<uint2*>(o);
}

// ---------------- weights -> bf16 MFMA fragment order ----------------
// frag idx in [0,2048): lt=idx&63, fid=idx>>6, s=fid>>3, nt=fid&7,
// n=nt*16+(lt&15), kb=s*32+(lt>>4)*8; element j: B[(kb+j)*128+n].
__global__ void wfrag_k(const float* __restrict__ W1, const float* __restrict__ root1,
                        __bf16* __restrict__ wf) {
    int mat = blockIdx.x >> 3;                       // 0..7 = W1[r], 8 = root1
    int idx = ((blockIdx.x & 7) << 8) + threadIdx.x; // 0..2047
    const float* B = (mat < 8) ? (W1 + (size_t)mat * DIM * DIM) : root1;
    int lt = idx & 63, fid = idx >> 6;
    int s = fid >> 3, nt = fid & 7;
    int n = nt * 16 + (lt & 15);
    int kb = s * 32 + (lt >> 4) * 8;
    bf16x8 v;
#pragma unroll
    for (int j = 0; j < 8; ++j) v[j] = (__bf16)B[(kb + j) * DIM + n];
    *reinterpret_cast<bf16x8*>(wf + ((size_t)mat * 2048 + idx) * 8) = v;
}

// ---------------- per-(t,rel) edge counts; seg = t*8 + r ----------------
__global__ void count_k(const int* __restrict__ r, const int* __restrict__ t, int* __restrict__ cnt) {
    int e = blockIdx.x * 256 + threadIdx.x;
    if (e < NE) atomicAdd(&cnt[t[e] * NR + r[e]], 1);
}

__global__ void inv_k(float* __restrict__ ci) {
    int i = blockIdx.x * 256 + threadIdx.x;
    if (i < NR * NN) {
        int c = reinterpret_cast<int*>(ci)[i];
        ci[i] = 1.0f / (float)(c > 1 ? c : 1);
    }
}

// ---------------- 3-pass exclusive scan over 400000 ints ----------------
__global__ __launch_bounds__(256) void scanA_k(const int* __restrict__ cnt, int* __restrict__ offs,
                                               int* __restrict__ part) {
    __shared__ int lds[256];
    const int tid = threadIdx.x;
    const int base = blockIdx.x * 1024 + tid * 4;
    int v[4] = {0, 0, 0, 0};
    if (base + 3 < NR * NN) {
        int4 q = *reinterpret_cast<const int4*>(cnt + base);
        v[0] = q.x; v[1] = q.y; v[2] = q.z; v[3] = q.w;
    } else {
#pragma unroll
        for (int j = 0; j < 4; ++j) if (base + j < NR * NN) v[j] = cnt[base + j];
    }
    int tsum = v[0] + v[1] + v[2] + v[3];
    lds[tid] = tsum;
    __syncthreads();
#pragma unroll
    for (int off = 1; off < 256; off <<= 1) {
        int val = (tid >= off) ? lds[tid - off] : 0;
        __syncthreads();
        if (tid >= off) lds[tid] += val;
        __syncthreads();
    }
    int run = lds[tid] - tsum;
#pragma unroll
    for (int j = 0; j < 4; ++j) {
        if (base + j < NR * NN) offs[base + j] = run;
        run += v[j];
    }
    if (tid == 255) part[blockIdx.x] = lds[255];
}

__global__ __launch_bounds__(512) void scanB_k(int* __restrict__ part) {
    __shared__ int lds[512];
    const int tid = threadIdx.x;
    int v = (tid < 391) ? part[tid] : 0;
    lds[tid] = v;
    __syncthreads();
#pragma unroll
    for (int off = 1; off < 512; off <<= 1) {
        int val = (tid >= off) ? lds[tid - off] : 0;
        __syncthreads();
        if (tid >= off) lds[tid] += val;
        __syncthreads();
    }
    part[tid] = lds[tid] - v;  // exclusive
}

__global__ __launch_bounds__(256) void scanC_k(int* __restrict__ offs, const int* __restrict__ part) {
    const int base = blockIdx.x * 1024 + threadIdx.x * 4;
    const int add = part[blockIdx.x];
#pragma unroll
    for (int j = 0; j < 4; ++j)
        if (base + j < NR * NN) offs[base + j] += add;
}

// ---------------- CSR fill: eh grouped by seg = t*8+r; offs -> end-offsets ----------------
__global__ void fill_k(const int* __restrict__ h, const int* __restrict__ r, const int* __restrict__ t,
                       int* __restrict__ offs, int* __restrict__ eh) {
    int e = blockIdx.x * 256 + threadIdx.x;
    if (e < NE) {
        int seg = t[e] * NR + r[e];
        int pos = atomicAdd(&offs[seg], 1);
        eh[pos] = h[e];
    }
}

// ---------------- wsum[r,h] += inv[t*8+r] per edge ----------------
__global__ void wsum_k(const int* __restrict__ h, const int* __restrict__ r, const int* __restrict__ t,
                       const float* __restrict__ inv, float* __restrict__ wsum) {
    int e = blockIdx.x * 256 + threadIdx.x;
    if (e < NE) {
        int re = r[e];
        atomicAdd(&wsum[re * NN + h[e]], inv[t[e] * NR + re]);
    }
}

// ---------------- fused layer 1: acc[t,:] = relu(b1 + sum_term A_term[t,:] @ W_term) ----------------
// term 0..7: A = mean of xb[h] over CSR segment (t, term); term 8: A = xb[t] (root).
// Per block: 64 targets x 128 cols. Gather into LDS A-tile, MFMA vs frag-order weights from L2.
__global__ __launch_bounds__(256) void rgcn_fused_k(
    const int* __restrict__ offs, const int* __restrict__ eh, const float* __restrict__ inv,
    const __bf16* __restrict__ xb, const __bf16* __restrict__ wf,
    const float* __restrict__ b1, float* __restrict__ acc)
{
    __shared__ __attribute__((aligned(16))) __bf16 Atile[64 * PAD];
    const int tid = threadIdx.x;
    const int wave = tid >> 6, lane = tid & 63, quad = lane >> 4;
    const int slot = tid >> 4, sl = tid & 15;   // 16 gather slots x 16 lanes
    const int tbase = blockIdx.x * 64;

    floatx4 C[8];
#pragma unroll
    for (int i = 0; i < 8; ++i) C[i] = (floatx4)0.f;

    for (int term = 0; term < 9; ++term) {
        // ---- gather phase: build A-tile rows ----
#pragma unroll
        for (int i = 0; i < 4; ++i) {
            int trow = slot + i * 16;
            int t = tbase + trow;
            bf16x8 out;
            if (t >= NN) {
#pragma unroll
                for (int j = 0; j < 8; ++j) out[j] = (__bf16)0.f;
            } else if (term == 8) {
                out = *reinterpret_cast<const bf16x8*>(xb + (size_t)t * DIM + sl * 8);
            } else {
                int seg = t * NR + term;
                int start = (seg == 0) ? 0 : offs[seg - 1];
                int end = offs[seg];
                float s0 = 0.f, s1 = 0.f, s2 = 0.f, s3 = 0.f,
                      s4 = 0.f, s5 = 0.f, s6 = 0.f, s7 = 0.f;
                for (int e = start; e < end; ++e) {
                    int he = eh[e];
                    bf16x8 y = *reinterpret_cast<const bf16x8*>(xb + (size_t)he * DIM + sl * 8);
                    s0 += (float)y[0]; s1 += (float)y[1]; s2 += (float)y[2]; s3 += (float)y[3];
                    s4 += (float)y[4]; s5 += (float)y[5]; s6 += (float)y[6]; s7 += (float)y[7];
                }
                float sc = inv[seg];
                out[0] = (__bf16)(s0 * sc); out[1] = (__bf16)(s1 * sc);
                out[2] = (__bf16)(s2 * sc); out[3] = (__bf16)(s3 * sc);
                out[4] = (__bf16)(s4 * sc); out[5] = (__bf16)(s5 * sc);
                out[6] = (__bf16)(s6 * sc); out[7] = (__bf16)(s7 * sc);
            }
            *reinterpret_cast<bf16x8*>(&Atile[trow * PAD + sl * 8]) = out;
        }
        __syncthreads();

        // ---- MFMA phase: C += A_tile @ W_term (B-frags straight from L2) ----
        const __bf16* wterm = wf + (size_t)term * 2048 * 8;
        const int arow = wave * 16 + (lane & 15);
#pragma unroll
        for (int s = 0; s < 4; ++s) {
            bf16x8 af = *reinterpret_cast<const bf16x8*>(&Atile[arow * PAD + s * 32 + quad * 8]);
#pragma unroll
            for (int nt = 0; nt < 8; ++nt) {
                bf16x8 bf = *reinterpret_cast<const bf16x8*>(
                    wterm + (size_t)((s * 8 + nt) * 64 + lane) * 8);
                C[nt] = __builtin_amdgcn_mfma_f32_16x16x32_bf16(af, bf, C[nt], 0, 0, 0);
            }
        }
        __syncthreads();
    }

    // ---- epilogue: bias + relu, single write of acc ----
    const int rb = tbase + wave * 16 + quad * 4, col = lane & 63 & 15;
#pragma unroll
    for (int nt = 0; nt < 8; ++nt) {
        int c = nt * 16 + (lane & 15);
        float badd = b1[c];
#pragma unroll
        for (int i = 0; i < 4; ++i) {
            int rr = rb + i;
            if (rr < NN) acc[(size_t)rr * DIM + c] = fmaxf(C[nt][i] + badd, 0.f);
        }
    }
    (void)col;
}

// ---------------- fused: S2[r,d] = sum_h wsum[r,h]*acc[h,d]; X1[d] = sum_h acc[h,d] ----------------
// acc is already post-relu.
__global__ __launch_bounds__(128) void s2x1_k(
    const float* __restrict__ acc, const float* __restrict__ wsum,
    float* __restrict__ S2, float* __restrict__ X1)
{
    const int d = threadIdx.x;
    float s[NR] = {0.f, 0.f, 0.f, 0.f, 0.f, 0.f, 0.f, 0.f};
    float x1 = 0.f;
    for (int n = blockIdx.x; n < NN; n += gridDim.x) {
        float v = acc[(size_t)n * DIM + d];
        x1 += v;
#pragma unroll
        for (int rr = 0; rr < NR; ++rr) s[rr] += wsum[rr * NN + n] * v;
    }
#pragma unroll
    for (int rr = 0; rr < NR; ++rr) atomicAdd(&S2[rr * DIM + d], s[rr]);
    atomicAdd(&X1[d], x1);
}

// ---------------- final: out = (S2.W2 + X1.root2)/N + b2 ----------------
__global__ __launch_bounds__(128) void final_k(
    const float* __restrict__ S2, const float* __restrict__ X1,
    const float* __restrict__ W2, const float* __restrict__ root2,
    const float* __restrict__ b2, float* __restrict__ out)
{
    const int o = threadIdx.x;
    float s = 0.f;
    for (int rr = 0; rr < NR; ++rr)
        for (int d = 0; d < DIM; ++d)
            s += S2[rr * DIM + d] * W2[((size_t)rr * DIM + d) * DIM + o];
    for (int d = 0; d < DIM; ++d)
        s += X1[d] * root2[d * DIM + o];
    out[o] = s * (1.0f / NN) + b2[o];
}

extern "C" void kernel_launch(void* const* d_in, const int* in_sizes, int n_in,
                              void* d_out, int out_size, void* d_ws, size_t ws_size,
                              hipStream_t stream)
{
    const int*   h     = (const int*)d_in[0];
    const int*   r     = (const int*)d_in[1];
    const int*   t     = (const int*)d_in[2];
    const float* x_emb = (const float*)d_in[3];
    const float* W1    = (const float*)d_in[4];
    const float* root1 = (const float*)d_in[5];
    const float* b1    = (const float*)d_in[6];
    const float* W2    = (const float*)d_in[7];
    const float* root2 = (const float*)d_in[8];
    const float* b2    = (const float*)d_in[9];

    float* ws   = (float*)d_ws;
    float* cnt  = ws + OFF_CNT;     // ints then inv floats in place
    float* wsum = ws + OFF_WSUM;
    float* S2   = ws + OFF_S2;
    float* X1   = ws + OFF_X1;
    int*   offs = (int*)(ws + OFF_OFFS);
    int*   part = (int*)(ws + OFF_PART);
    int*   eh   = (int*)(ws + OFF_EH);
    __bf16* xb  = (__bf16*)(ws + OFF_XB);
    __bf16* wf  = (__bf16*)(ws + OFF_WF);
    float* acc  = ws + OFF_ACC;

    // zero counts + wsum + S2 + X1 (ws re-poisoned to 0xAA before every timed launch)
    hipMemsetAsync(ws, 0, (size_t)801152 * sizeof(float), stream);

    cvt_bf16_k<<<6250, 256, 0, stream>>>(x_emb, xb);
    wfrag_k<<<72, 256, 0, stream>>>(W1, root1, wf);
    count_k<<<3125, 256, 0, stream>>>(r, t, (int*)cnt);

    // exclusive scan cnt -> offs
    scanA_k<<<391, 256, 0, stream>>>((const int*)cnt, offs, part);
    scanB_k<<<1, 512, 0, stream>>>(part);
    scanC_k<<<391, 256, 0, stream>>>(offs, part);

    inv_k<<<1563, 256, 0, stream>>>(cnt);                 // cnt -> inv in place
    fill_k<<<3125, 256, 0, stream>>>(h, r, t, offs, eh);  // offs -> end-offsets
    wsum_k<<<3125, 256, 0, stream>>>(h, r, t, cnt, wsum);

    // fused layer 1: gather-mean + 9-term MFMA + bias + relu
    rgcn_fused_k<<<782, 256, 0, stream>>>(offs, eh, cnt, xb, wf, b1, acc);

    // layer 2 collapses to dense contractions (mean over nodes commutes with W2/root2)
    s2x1_k<<<256, 128, 0, stream>>>(acc, wsum, S2, X1);
    final_k<<<1, 128, 0, stream>>>(S2, X1, W2, root2, b2, (float*)d_out);
}

// Round 4
// 417.570 us; speedup vs baseline: 4.6204x; 1.0981x over previous
//
#include <hip/hip_runtime.h>
#include <hip/hip_bf16.h>

#define NN 50000
#define NR 8
#define DIM 128
#define NE 800000
#define PAD 136   // A-tile row stride in bf16 (128 + 8): 2-way LDS conflicts only
#define CAP 2048  // per-block staged edge capacity (mean 1024, sd ~32 -> never exceeded; guarded anyway)

using floatx4 = __attribute__((ext_vector_type(4))) float;
using bf16x8  = __attribute__((ext_vector_type(8))) __bf16;

// ---------------- workspace layout (in floats) ----------------
// zeroed region: [0, 800000) = cnt + wsum
#define OFF_CNT   0u         // 400000: int counts -> float inv in place (seg = t*8+r)
#define OFF_WSUM  400000u    // 400000: wsum[r*NN+h] fp32 atomic accum
#define OFF_S2    800000u    // 1024: S2 (written by s2red_k)   [contiguous with X1]
#define OFF_X1    801024u    // 128: X1sum (written by s2red_k)
#define OFF_OFFS  801152u    // 400000 ints: CSR offsets (end-offsets after fill)
#define OFF_PART  1201152u   // 512 ints: scan partials
#define OFF_EH    1201664u   // 800000 ints: CSR-sorted edge head indices
#define OFF_XB    2001664u   // 6.4M bf16: x_emb in bf16
#define OFF_WF    5201664u   // 9*2048*8 bf16 = 73728 floats: weights in MFMA frag order
#define OFF_ACC   5275392u   // 6.4M floats: layer-1 POST-relu activations
#define OFF_S2P   11675392u  // 512*1280: S2/X1 block partials
// total 12,330,752 floats = 49.3 MB

// ---------------- bf16 cast of x_emb (x4 vectorized) ----------------
__global__ void cvt_bf16_k(const float* __restrict__ x, __bf16* __restrict__ xb) {
    int i = (blockIdx.x * 256 + threadIdx.x) * 4;
    float4 v = *reinterpret_cast<const float4*>(x + i);
    __bf16 o[4] = {(__bf16)v.x, (__bf16)v.y, (__bf16)v.z, (__bf16)v.w};
    *reinterpret_cast<uint2*>(xb + i) = *reinterpret_cast<uint2*>(o);
}

// ---------------- weights -> bf16 MFMA fragment order ----------------
__global__ void wfrag_k(const float* __restrict__ W1, const float* __restrict__ root1,
                        __bf16* __restrict__ wf) {
    int mat = blockIdx.x >> 3;                       // 0..7 = W1[r], 8 = root1
    int idx = ((blockIdx.x & 7) << 8) + threadIdx.x; // 0..2047
    const float* B = (mat < 8) ? (W1 + (size_t)mat * DIM * DIM) : root1;
    int lt = idx & 63, fid = idx >> 6;
    int s = fid >> 3, nt = fid & 7;
    int n = nt * 16 + (lt & 15);
    int kb = s * 32 + (lt >> 4) * 8;
    bf16x8 v;
#pragma unroll
    for (int j = 0; j < 8; ++j) v[j] = (__bf16)B[(kb + j) * DIM + n];
    *reinterpret_cast<bf16x8*>(wf + ((size_t)mat * 2048 + idx) * 8) = v;
}

// ---------------- per-(t,rel) edge counts; seg = t*8 + r ----------------
__global__ void count_k(const int* __restrict__ r, const int* __restrict__ t, int* __restrict__ cnt) {
    int e = blockIdx.x * 256 + threadIdx.x;
    if (e < NE) atomicAdd(&cnt[t[e] * NR + r[e]], 1);
}

// ---------------- scan pass A: block-local exclusive scan + inv in place ----------------
__global__ __launch_bounds__(256) void scanA_k(const int* cnt, float* invout,
                                               int* __restrict__ offs, int* __restrict__ part) {
    __shared__ int lds[256];
    const int tid = threadIdx.x;
    const int base = blockIdx.x * 1024 + tid * 4;
    int v[4] = {0, 0, 0, 0};
    if (base + 3 < NR * NN) {
        int4 q = *reinterpret_cast<const int4*>(cnt + base);
        v[0] = q.x; v[1] = q.y; v[2] = q.z; v[3] = q.w;
    } else {
#pragma unroll
        for (int j = 0; j < 4; ++j) if (base + j < NR * NN) v[j] = cnt[base + j];
    }
    int tsum = v[0] + v[1] + v[2] + v[3];
    lds[tid] = tsum;
    __syncthreads();
#pragma unroll
    for (int off = 1; off < 256; off <<= 1) {
        int val = (tid >= off) ? lds[tid - off] : 0;
        __syncthreads();
        if (tid >= off) lds[tid] += val;
        __syncthreads();
    }
    int run = lds[tid] - tsum;
#pragma unroll
    for (int j = 0; j < 4; ++j) {
        if (base + j < NR * NN) {
            offs[base + j] = run;
            invout[base + j] = 1.0f / (float)(v[j] > 1 ? v[j] : 1);  // inv fused in
        }
        run += v[j];
    }
    if (tid == 255) part[blockIdx.x] = lds[255];
}

__global__ __launch_bounds__(512) void scanB_k(int* __restrict__ part) {
    __shared__ int lds[512];
    const int tid = threadIdx.x;
    int v = (tid < 391) ? part[tid] : 0;
    lds[tid] = v;
    __syncthreads();
#pragma unroll
    for (int off = 1; off < 512; off <<= 1) {
        int val = (tid >= off) ? lds[tid - off] : 0;
        __syncthreads();
        if (tid >= off) lds[tid] += val;
        __syncthreads();
    }
    part[tid] = lds[tid] - v;  // exclusive
}

__global__ __launch_bounds__(256) void scanC_k(int* __restrict__ offs, const int* __restrict__ part) {
    const int base = blockIdx.x * 1024 + threadIdx.x * 4;
    const int add = part[blockIdx.x];
#pragma unroll
    for (int j = 0; j < 4; ++j)
        if (base + j < NR * NN) offs[base + j] += add;
}

// ---------------- merged CSR fill + wsum: one pass over edges ----------------
__global__ void fillw_k(const int* __restrict__ h, const int* __restrict__ r, const int* __restrict__ t,
                        int* __restrict__ offs, int* __restrict__ eh,
                        const float* __restrict__ inv, float* __restrict__ wsum) {
    int e = blockIdx.x * 256 + threadIdx.x;
    if (e < NE) {
        int he = h[e], re = r[e];
        int seg = t[e] * NR + re;
        int pos = atomicAdd(&offs[seg], 1);   // offs -> end-offsets
        eh[pos] = he;
        atomicAdd(&wsum[re * NN + he], inv[seg]);
    }
}

// ---------------- fused layer 1: acc[t,:] = relu(b1 + sum_term A_term[t,:] @ W_term) ----------------
// Gather restructured for MLP: CSR slice staged in LDS; 4 rows' segment walks
// interleaved branch-free -> 4 independent xb loads in flight per thread.
__global__ __launch_bounds__(256) void rgcn_fused_k(
    const int* __restrict__ offs, const int* __restrict__ eh, const float* __restrict__ inv,
    const __bf16* __restrict__ xb, const __bf16* __restrict__ wf,
    const float* __restrict__ b1, float* __restrict__ acc)
{
    __shared__ __attribute__((aligned(16))) __bf16 Atile[64 * PAD];  // 17.4 KB
    __shared__ int   loffs[513];
    __shared__ float invl[512];
    __shared__ int   eidx[CAP];                                      // 8 KB
    const int tid = threadIdx.x;
    const int wave = tid >> 6, lane = tid & 63, quad = lane >> 4;
    const int slot = tid >> 4, sl = tid & 15;   // 16 gather slots x 16 lanes
    const int tbase = blockIdx.x * 64;
    const int segbase = tbase * NR;

    // ---- stage offsets + inv for the block's 512 segments (coalesced) ----
    for (int j = tid; j < 513; j += 256) {
        int g = segbase + j - 1;
        loffs[j] = (g < 0) ? 0 : offs[g > NR * NN - 1 ? NR * NN - 1 : g];
    }
    for (int j = tid; j < 512; j += 256) {
        int g = segbase + j;
        invl[j] = inv[g > NR * NN - 1 ? NR * NN - 1 : g];
    }
    __syncthreads();
    const int s0 = loffs[0];
    const int Eb = loffs[512] - s0;
    for (int k = tid; k < Eb && k < CAP; k += 256)
        eidx[k] = eh[s0 + k];
    __syncthreads();

    floatx4 C[8];
#pragma unroll
    for (int i = 0; i < 8; ++i) C[i] = (floatx4)0.f;

    for (int term = 0; term < 9; ++term) {
        if (term == 8) {       // root term: A row = xb[t]
#pragma unroll
            for (int i = 0; i < 4; ++i) {
                int trow = slot + i * 16;
                int t = tbase + trow;
                bf16x8 out;
                if (t < NN) {
                    out = *reinterpret_cast<const bf16x8*>(xb + (size_t)t * DIM + sl * 8);
                } else {
#pragma unroll
                    for (int j = 0; j < 8; ++j) out[j] = (__bf16)0.f;
                }
                *reinterpret_cast<bf16x8*>(&Atile[trow * PAD + sl * 8]) = out;
            }
        } else {
            int st[4], ln[4];
            float a[4][8];
#pragma unroll
            for (int i = 0; i < 4; ++i) {
                int j = (slot + i * 16) * 8 + term;
                int b = loffs[j];
                st[i] = b - s0;
                ln[i] = loffs[j + 1] - b;
#pragma unroll
                for (int k = 0; k < 8; ++k) a[i][k] = 0.f;
            }
            int mx = max(max(ln[0], ln[1]), max(ln[2], ln[3]));
            for (int p = 0; p < mx; ++p) {
#pragma unroll
                for (int i = 0; i < 4; ++i) {
                    // branch-free: clamp position, weight 0/1 -> load always issued
                    int pos = st[i] + p;
                    int pc = pos < Eb - 1 ? pos : Eb - 1;
                    if (pc < 0) pc = 0;
                    int he = (pc < CAP) ? eidx[pc] : eh[s0 + pc];
                    float w = (p < ln[i]) ? 1.f : 0.f;
                    bf16x8 y = *reinterpret_cast<const bf16x8*>(xb + (size_t)he * DIM + sl * 8);
#pragma unroll
                    for (int k = 0; k < 8; ++k) a[i][k] += w * (float)y[k];
                }
            }
#pragma unroll
            for (int i = 0; i < 4; ++i) {
                int trow = slot + i * 16;
                float sc = invl[trow * 8 + term];
                bf16x8 out;
#pragma unroll
                for (int k = 0; k < 8; ++k) out[k] = (__bf16)(a[i][k] * sc);
                *reinterpret_cast<bf16x8*>(&Atile[trow * PAD + sl * 8]) = out;
            }
        }
        __syncthreads();

        // ---- MFMA: C += A_tile @ W_term (B-frags from L2, frag order) ----
        const __bf16* wterm = wf + (size_t)term * 2048 * 8;
        const int arow = wave * 16 + (lane & 15);
#pragma unroll
        for (int s = 0; s < 4; ++s) {
            bf16x8 af = *reinterpret_cast<const bf16x8*>(&Atile[arow * PAD + s * 32 + quad * 8]);
#pragma unroll
            for (int nt = 0; nt < 8; ++nt) {
                bf16x8 bf = *reinterpret_cast<const bf16x8*>(
                    wterm + (size_t)((s * 8 + nt) * 64 + lane) * 8);
                C[nt] = __builtin_amdgcn_mfma_f32_16x16x32_bf16(af, bf, C[nt], 0, 0, 0);
            }
        }
        __syncthreads();
    }

    // ---- epilogue: bias + relu, single write of acc ----
    const int rb = tbase + wave * 16 + quad * 4;
#pragma unroll
    for (int nt = 0; nt < 8; ++nt) {
        int c = nt * 16 + (lane & 15);
        float badd = b1[c];
#pragma unroll
        for (int i = 0; i < 4; ++i) {
            int rr = rb + i;
            if (rr < NN) acc[(size_t)rr * DIM + c] = fmaxf(C[nt][i] + badd, 0.f);
        }
    }
}

// ---------------- S2/X1 block partials (no atomics): acc is post-relu ----------------
__global__ __launch_bounds__(128) void s2x1_k(
    const float* __restrict__ acc, const float* __restrict__ wsum, float* __restrict__ S2P)
{
    const int d = threadIdx.x;
    float s[NR] = {0.f, 0.f, 0.f, 0.f, 0.f, 0.f, 0.f, 0.f};
    float x1 = 0.f;
    for (int n = blockIdx.x; n < NN; n += gridDim.x) {
        float v = acc[(size_t)n * DIM + d];
        x1 += v;
#pragma unroll
        for (int rr = 0; rr < NR; ++rr) s[rr] += wsum[rr * NN + n] * v;
    }
    float* row = S2P + (size_t)blockIdx.x * 1280;
#pragma unroll
    for (int rr = 0; rr < NR; ++rr) row[rr * DIM + d] = s[rr];
    row[1024 + d] = x1;
}

__global__ void s2red_k(const float* __restrict__ S2P, float* __restrict__ S2X1) {
    int c = blockIdx.x * 256 + threadIdx.x;   // 0..1279
    if (c < 1280) {
        float s = 0.f;
        for (int b = 0; b < 512; ++b) s += S2P[(size_t)b * 1280 + c];
        S2X1[c] = s;
    }
}

// ---------------- final: out = (S2.W2 + X1.root2)/N + b2 ----------------
__global__ __launch_bounds__(128) void final_k(
    const float* __restrict__ S2, const float* __restrict__ X1,
    const float* __restrict__ W2, const float* __restrict__ root2,
    const float* __restrict__ b2, float* __restrict__ out)
{
    const int o = threadIdx.x;
    float s = 0.f;
    for (int rr = 0; rr < NR; ++rr)
        for (int d = 0; d < DIM; ++d)
            s += S2[rr * DIM + d] * W2[((size_t)rr * DIM + d) * DIM + o];
    for (int d = 0; d < DIM; ++d)
        s += X1[d] * root2[d * DIM + o];
    out[o] = s * (1.0f / NN) + b2[o];
}

extern "C" void kernel_launch(void* const* d_in, const int* in_sizes, int n_in,
                              void* d_out, int out_size, void* d_ws, size_t ws_size,
                              hipStream_t stream)
{
    const int*   h     = (const int*)d_in[0];
    const int*   r     = (const int*)d_in[1];
    const int*   t     = (const int*)d_in[2];
    const float* x_emb = (const float*)d_in[3];
    const float* W1    = (const float*)d_in[4];
    const float* root1 = (const float*)d_in[5];
    const float* b1    = (const float*)d_in[6];
    const float* W2    = (const float*)d_in[7];
    const float* root2 = (const float*)d_in[8];
    const float* b2    = (const float*)d_in[9];

    float* ws   = (float*)d_ws;
    float* cnt  = ws + OFF_CNT;     // int counts then inv floats in place
    float* wsum = ws + OFF_WSUM;
    float* S2   = ws + OFF_S2;
    float* X1   = ws + OFF_X1;
    int*   offs = (int*)(ws + OFF_OFFS);
    int*   part = (int*)(ws + OFF_PART);
    int*   eh   = (int*)(ws + OFF_EH);
    __bf16* xb  = (__bf16*)(ws + OFF_XB);
    __bf16* wf  = (__bf16*)(ws + OFF_WF);
    float* acc  = ws + OFF_ACC;
    float* S2P  = ws + OFF_S2P;

    // zero counts + wsum (ws re-poisoned to 0xAA before every timed launch)
    hipMemsetAsync(ws, 0, (size_t)800000 * sizeof(float), stream);

    cvt_bf16_k<<<6250, 256, 0, stream>>>(x_emb, xb);
    wfrag_k<<<72, 256, 0, stream>>>(W1, root1, wf);
    count_k<<<3125, 256, 0, stream>>>(r, t, (int*)cnt);

    // exclusive scan cnt -> offs (+inv fused into pass A)
    scanA_k<<<391, 256, 0, stream>>>((const int*)cnt, cnt, offs, part);
    scanB_k<<<1, 512, 0, stream>>>(part);
    scanC_k<<<391, 256, 0, stream>>>(offs, part);

    // merged fill + wsum single edge pass
    fillw_k<<<3125, 256, 0, stream>>>(h, r, t, offs, eh, cnt, wsum);

    // fused layer 1: gather-mean + 9-term MFMA + bias + relu
    rgcn_fused_k<<<782, 256, 0, stream>>>(offs, eh, cnt, xb, wf, b1, acc);

    // layer 2 collapses to dense contractions (mean over nodes commutes with W2/root2)
    s2x1_k<<<512, 128, 0, stream>>>(acc, wsum, S2P);
    s2red_k<<<5, 256, 0, stream>>>(S2P, S2);   // writes S2 then X1 (contiguous)
    final_k<<<1, 128, 0, stream>>>(S2, X1, W2, root2, b2, (float*)d_out);
}